// Round 4
// baseline (354782.886 us; speedup 1.0000x reference)
//
#include <hip/hip_runtime.h>
#include <cstdio>
#include <cstddef>

typedef unsigned short u16;
typedef unsigned int u32;

#define BB   128
#define TT   400
#define EE   512
#define HH   256
#define NMEL 80
#define AA   128
#define DD   1024
#define T3   1200

__device__ __forceinline__ float b2f(u16 h) { return __uint_as_float(((u32)h) << 16); }
__device__ __forceinline__ u16 f2b(float f) {
    u32 x = __float_as_uint(f);
    u32 r = (x + 0x7FFFu + ((x >> 16) & 1u)) >> 16;
    return (u16)r;
}
__device__ __forceinline__ float sigm(float x) { return 1.0f / (1.0f + __expf(-x)); }

// dual-dtype EXTERNAL-input loads (F32=1: buffer is float32; F32=0: bf16 u16)
template<int F32> __device__ __forceinline__ float ldf(const void* p, size_t i) {
    if (F32) return ((const float*)p)[i];
    return b2f(((const u16*)p)[i]);
}
template<int F32> __device__ __forceinline__ float4 ldf4(const void* p, size_t i) {
    if (F32) return *(const float4*)((const float*)p + i);
    ushort4 w = *(const ushort4*)((const u16*)p + i);
    return make_float4(b2f(w.x), b2f(w.y), b2f(w.z), b2f(w.w));
}
template<int F32> __device__ __forceinline__ void stf(void* p, size_t i, float v) {
    if (F32) ((float*)p)[i] = v;
    else ((u16*)p)[i] = f2b(v);
}
__device__ __forceinline__ void dotf(float& a, float4 w, float4 x) {
    a += w.x * x.x; a += w.y * x.y; a += w.z * x.z; a += w.w * x.w;
}

// ---------------- dtype detector (probe emb) ----------------
__global__ __launch_bounds__(256) void k_detect(const void* emb, int* flag) {
    int tid = threadIdx.x;
    const u16* p = (const u16*)emb;
    int insane = 0;
    for (int i = tid; i < 4096; i += 256) {
        u16 h = p[2 * i];
        u32 ex = (h >> 7) & 0xFF;
        if (ex < 96 || ex > 159) insane++;
    }
    __shared__ int red[256];
    red[tid] = insane; __syncthreads();
    for (int st = 128; st > 0; st >>= 1) {
        if (tid < st) red[tid] += red[tid + st];
        __syncthreads();
    }
    if (tid == 0) *flag = (red[0] > 1024) ? 1 : 0;
}

// ---------------- embedding: X[b,e,t] = emb[text[b,t], e]  (fp32 staging) ------
template<int F32> __device__ __forceinline__ void embed_body(const int* text, const void* emb, float* X) {
    int e = blockIdx.x, b = blockIdx.y;
    for (int t = threadIdx.x; t < TT; t += 256) {
        int v = text[b * TT + t];
        X[((size_t)b * EE + e) * TT + t] = ldf<F32>(emb, (size_t)v * EE + e);
    }
}
__global__ __launch_bounds__(256) void k_embed(const int* text, const void* emb, float* X, const int* flag) {
    if (*flag) embed_body<1>(text, emb, X); else embed_body<0>(text, emb, X);
}

// ---------------- encoder conv5 pad2 + bias + relu -> fp32 Y ----------------
template<int F32> __device__ __forceinline__
void encconv_body(const float* X, const void* W, const void* bias, float* Y, float* xs) {
    int t0 = blockIdx.x * 64, o0 = blockIdx.y * 32, b = blockIdx.z;
    int tid = threadIdx.x;
    int ol = tid >> 3, tg = tid & 7;
    int o = o0 + ol, tl = tg * 8;
    float acc[8];
    float bv = ldf<F32>(bias, o);
    #pragma unroll
    for (int j = 0; j < 8; ++j) acc[j] = bv;
    for (int q = 0; q < 4; ++q) {            // 4 x 128-channel tiles (LDS 34.8KB)
        __syncthreads();
        for (int idx = tid; idx < 128 * 68; idx += 256) {
            int il = idx / 68, rest = idx - il * 68;
            int t = t0 - 2 + rest;
            float v = 0.f;
            if (t >= 0 && t < TT) v = X[((size_t)b * EE + q * 128 + il) * TT + t];
            xs[idx] = v;
        }
        __syncthreads();
        size_t wbase = ((size_t)o * EE + q * 128) * 5;
        for (int il = 0; il < 128; ++il) {
            float xv[12];
            #pragma unroll
            for (int j = 0; j < 12; ++j) xv[j] = xs[il * 68 + tl + j];
            #pragma unroll
            for (int k = 0; k < 5; ++k) {
                float w = ldf<F32>(W, wbase + il * 5 + k);
                #pragma unroll
                for (int j = 0; j < 8; ++j) acc[j] += w * xv[j + k];
            }
        }
    }
    #pragma unroll
    for (int j = 0; j < 8; ++j) {
        int t = t0 + tl + j;
        if (t < TT) Y[((size_t)b * EE + o) * TT + t] = acc[j] > 0.f ? acc[j] : 0.f;
    }
}
__global__ __launch_bounds__(256) void k_encconv(const float* X, const void* W, const void* bias, float* Y, const int* flag) {
    __shared__ float xs[128 * 68];
    if (*flag) encconv_body<1>(X, W, bias, Y, xs); else encconv_body<0>(X, W, bias, Y, xs);
}

// ---------------- BatchNorm stats (train mode, biased var); input fp32 or bf16 ----
template<int INF32> __device__ __forceinline__
void bnstats_body(const void* Y, float* mu, float* rs, int L, int C, int Bn) {
    int o = blockIdx.x, tid = threadIdx.x;
    float s = 0.f, s2 = 0.f;
    for (int b = 0; b < Bn; ++b) {
        size_t base = ((size_t)b * C + o) * L;
        for (int t = tid; t < L; t += 256) {
            float v = INF32 ? ((const float*)Y)[base + t] : b2f(((const u16*)Y)[base + t]);
            s += v; s2 += v * v;
        }
    }
    __shared__ float r1[256], r2[256];
    r1[tid] = s; r2[tid] = s2; __syncthreads();
    for (int st = 128; st > 0; st >>= 1) {
        if (tid < st) { r1[tid] += r1[tid + st]; r2[tid] += r2[tid + st]; }
        __syncthreads();
    }
    if (tid == 0) {
        float n = (float)Bn * (float)L;
        float m = r1[0] / n;
        float var = r2[0] / n - m * m;
        mu[o] = m;
        rs[o] = 1.0f / sqrtf(var + 1e-5f);
    }
}
__global__ __launch_bounds__(256) void k_bnstats(const void* Y, float* mu, float* rs, int L, int C, int Bn, int inf32) {
    if (inf32) bnstats_body<1>(Y, mu, rs, L, C, Bn); else bnstats_body<0>(Y, mu, rs, L, C, Bn);
}

// ---------------- BN apply + transpose [B,C,T] -> [T,B,C], fp32->fp32 ----------------
template<int F32> __device__ __forceinline__
void bnapply_body(const float* Y, const float* mu, const float* rs, const void* g, const void* beta,
                  float* H, float* tile) {  // tile: 64*65
    int t0 = blockIdx.x * 64, c0 = blockIdx.y * 64, b = blockIdx.z;
    int tid = threadIdx.x;
    for (int idx = tid; idx < 64 * 64; idx += 256) {
        int cl = idx >> 6, tl = idx & 63;
        int t = t0 + tl, c = c0 + cl;
        float v = 0.f;
        if (t < TT) v = Y[((size_t)b * EE + c) * TT + t];
        tile[cl * 65 + tl] = (v - mu[c]) * rs[c] * ldf<F32>(g, c) + ldf<F32>(beta, c);
    }
    __syncthreads();
    for (int idx = tid; idx < 64 * 64; idx += 256) {
        int tl = idx >> 6, cl = idx & 63;
        int t = t0 + tl;
        if (t < TT) H[((size_t)t * BB + b) * EE + c0 + cl] = tile[cl * 65 + tl];
    }
}
__global__ __launch_bounds__(256) void k_bnapply(const float* Y, const float* mu, const float* rs,
                                                 const void* g, const void* beta, float* H, const int* flag) {
    __shared__ float tile[64 * 65];
    if (*flag) bnapply_body<1>(Y, mu, rs, g, beta, H, tile); else bnapply_body<0>(Y, mu, rs, g, beta, H, tile);
}

// ---------------- one biLSTM layer: fp32 in/out, fused xW + hW, 2 batch rows/block ---
template<int F32> __device__ __forceinline__
void lstm_body(const float* Hin, float* Hout, const void* Wih_all, const void* Whh_all,
               const void* b_all, int layer, float* xsh, float* hsh) {  // xsh: 1024, hsh: 512
    int d = blockIdx.x >> 6;            // 0 fwd, 1 bwd
    int b0 = (blockIdx.x & 63) * 2;
    int u = threadIdx.x;                // hidden unit
    size_t wihB = (size_t)(layer * 2 + d) * 1024 * 512;
    size_t whhB = (size_t)(layer * 2 + d) * 1024 * 256;
    size_t bB   = (size_t)(layer * 2 + d) * 1024;
    float bi_ = ldf<F32>(b_all, bB + u),       bf_ = ldf<F32>(b_all, bB + 256 + u);
    float bg_ = ldf<F32>(b_all, bB + 512 + u), bo_ = ldf<F32>(b_all, bB + 768 + u);
    size_t wi0 = wihB + (size_t)u * 512;
    size_t wi1 = wihB + (size_t)(256 + u) * 512;
    size_t wi2 = wihB + (size_t)(512 + u) * 512;
    size_t wi3 = wihB + (size_t)(768 + u) * 512;
    size_t wh0 = whhB + (size_t)u * 256;
    size_t wh1 = whhB + (size_t)(256 + u) * 256;
    size_t wh2 = whhB + (size_t)(512 + u) * 256;
    size_t wh3 = whhB + (size_t)(768 + u) * 256;
    float c0v = 0.f, c1v = 0.f;
    hsh[u] = 0.f; hsh[256 + u] = 0.f;
    for (int s = 0; s < TT; ++s) {
        int t = d ? (TT - 1 - s) : s;
        __syncthreads();
        const float* src = Hin + ((size_t)t * BB + b0) * EE;   // two consecutive b-rows
        xsh[u] = src[u];             xsh[256 + u] = src[256 + u];
        xsh[512 + u] = src[512 + u]; xsh[768 + u] = src[768 + u];
        __syncthreads();
        float a0i = bi_, a0f = bf_, a0g = bg_, a0o = bo_;
        float a1i = bi_, a1f = bf_, a1g = bg_, a1o = bo_;
        for (int k = 0; k < 512; k += 4) {
            float4 x0 = *(const float4*)&xsh[k];
            float4 x1 = *(const float4*)&xsh[512 + k];
            float4 w;
            w = ldf4<F32>(Wih_all, wi0 + k); dotf(a0i, w, x0); dotf(a1i, w, x1);
            w = ldf4<F32>(Wih_all, wi1 + k); dotf(a0f, w, x0); dotf(a1f, w, x1);
            w = ldf4<F32>(Wih_all, wi2 + k); dotf(a0g, w, x0); dotf(a1g, w, x1);
            w = ldf4<F32>(Wih_all, wi3 + k); dotf(a0o, w, x0); dotf(a1o, w, x1);
        }
        for (int k = 0; k < 256; k += 4) {
            float4 h0 = *(const float4*)&hsh[k];
            float4 h1 = *(const float4*)&hsh[256 + k];
            float4 w;
            w = ldf4<F32>(Whh_all, wh0 + k); dotf(a0i, w, h0); dotf(a1i, w, h1);
            w = ldf4<F32>(Whh_all, wh1 + k); dotf(a0f, w, h0); dotf(a1f, w, h1);
            w = ldf4<F32>(Whh_all, wh2 + k); dotf(a0g, w, h0); dotf(a1g, w, h1);
            w = ldf4<F32>(Whh_all, wh3 + k); dotf(a0o, w, h0); dotf(a1o, w, h1);
        }
        float i0 = sigm(a0i), f0 = sigm(a0f), g0 = tanhf(a0g), o0v = sigm(a0o);
        c0v = f0 * c0v + i0 * g0;
        float h0v = o0v * tanhf(c0v);
        float i1 = sigm(a1i), f1 = sigm(a1f), g1 = tanhf(a1g), o1v = sigm(a1o);
        c1v = f1 * c1v + i1 * g1;
        float h1v = o1v * tanhf(c1v);
        __syncthreads();
        hsh[u] = h0v; hsh[256 + u] = h1v;
        Hout[((size_t)t * BB + b0) * EE + d * HH + u]     = h0v;
        Hout[((size_t)t * BB + b0 + 1) * EE + d * HH + u] = h1v;
    }
}
__global__ __launch_bounds__(256) void k_lstm(const float* Hin, float* Hout, const void* Wih, const void* Whh,
                                              const void* bb, int layer, const int* flag) {
    __shared__ __align__(16) float xsh[1024];
    __shared__ __align__(16) float hsh[512];
    if (*flag) lstm_body<1>(Hin, Hout, Wih, Whh, bb, layer, xsh, hsh);
    else       lstm_body<0>(Hin, Hout, Wih, Whh, bb, layer, xsh, hsh);
}

// ---------------- pm[t,b,a] = memory[b,t,:] . Wm[a,:]  (memory fp32) ----------------
template<int F32> __device__ __forceinline__
void pm_body(const float* H1, const void* Wm, float* PM, float* xsh) {  // xsh: 8*512
    int t0 = blockIdx.x * 8, b = blockIdx.y;
    int tid = threadIdx.x;
    for (int idx = tid; idx < 8 * 512; idx += 128) {
        int tt = idx >> 9, k = idx & 511;
        xsh[tt * 512 + k] = H1[((size_t)(t0 + tt) * BB + b) * EE + k];
    }
    __syncthreads();
    size_t wrow = (size_t)tid * 512;
    float acc[8] = {0, 0, 0, 0, 0, 0, 0, 0};
    for (int k = 0; k < 512; k += 4) {
        float4 w = ldf4<F32>(Wm, wrow + k);
        #pragma unroll
        for (int tt = 0; tt < 8; ++tt) {
            float4 x = *(const float4*)&xsh[tt * 512 + k];
            acc[tt] += w.x * x.x; acc[tt] += w.y * x.y; acc[tt] += w.z * x.z; acc[tt] += w.w * x.w;
        }
    }
    #pragma unroll
    for (int tt = 0; tt < 8; ++tt)
        PM[((size_t)(t0 + tt) * BB + b) * AA + tid] = acc[tt];
}
__global__ __launch_bounds__(128) void k_pm(const float* H1, const void* Wm, float* PM, const int* flag) {
    __shared__ __align__(16) float xsh[8 * 512];
    if (*flag) pm_body<1>(H1, Wm, PM, xsh); else pm_body<0>(H1, Wm, PM, xsh);
}

// ---------------- prenet for all steps (teacher forced), fp32 out ----------------
template<int F32> __device__ __forceinline__
void prenet_body(const void* mels, const void* W1, const void* b1, const void* W2, const void* b2,
                 float* PRE, float* insh, float* p1sh) {  // insh 16*80, p1sh 16*256
    int b0 = blockIdx.x * 16, t = blockIdx.y;
    int tid = threadIdx.x;
    for (int idx = tid; idx < 16 * 80; idx += 256) {
        int bi = idx / 80, m = idx - bi * 80;
        insh[bi * 80 + m] = (t == 0) ? 0.f : ldf<F32>(mels, ((size_t)(b0 + bi) * NMEL + m) * TT + (t - 1));
    }
    __syncthreads();
    int j = tid;
    float acc[16];
    float bv = ldf<F32>(b1, j);
    #pragma unroll
    for (int bi = 0; bi < 16; ++bi) acc[bi] = bv;
    for (int m = 0; m < 80; ++m) {
        float w = ldf<F32>(W1, (size_t)j * 80 + m);   // W1: [256,80]
        #pragma unroll
        for (int bi = 0; bi < 16; ++bi) acc[bi] += w * insh[bi * 80 + m];
    }
    #pragma unroll
    for (int bi = 0; bi < 16; ++bi) p1sh[bi * 256 + j] = acc[bi] > 0.f ? acc[bi] : 0.f;
    __syncthreads();
    float acc2[16];
    float bv2 = ldf<F32>(b2, j);
    #pragma unroll
    for (int bi = 0; bi < 16; ++bi) acc2[bi] = bv2;
    size_t w2row = (size_t)j * 256;
    for (int k = 0; k < 256; k += 4) {
        float4 w = ldf4<F32>(W2, w2row + k);
        #pragma unroll
        for (int bi = 0; bi < 16; ++bi) {
            float4 p = *(const float4*)&p1sh[bi * 256 + k];
            acc2[bi] += w.x * p.x; acc2[bi] += w.y * p.y; acc2[bi] += w.z * p.z; acc2[bi] += w.w * p.w;
        }
    }
    #pragma unroll
    for (int bi = 0; bi < 16; ++bi) {
        float v = acc2[bi] > 0.f ? acc2[bi] : 0.f;
        PRE[((size_t)t * BB + b0 + bi) * HH + j] = v;
    }
}
__global__ __launch_bounds__(256) void k_prenet(const void* mels, const void* W1, const void* b1,
                                                const void* W2, const void* b2, float* PRE, const int* flag) {
    __shared__ __align__(16) float insh[16 * 80];
    __shared__ __align__(16) float p1sh[16 * 256];
    if (*flag) prenet_body<1>(mels, W1, b1, W2, b2, PRE, insh, p1sh);
    else       prenet_body<0>(mels, W1, b1, W2, b2, PRE, insh, p1sh);
}

// ---------------- effective 1-channel location kernel (both cum channels equal) -----
__global__ void k_weff(const void* Wloc, float* weff, const int* flag) {
    int a = threadIdx.x;
    if (*flag) {
        for (int k = 0; k < 31; ++k)
            weff[a * 31 + k] = ldf<1>(Wloc, (size_t)(a * 2) * 31 + k) + ldf<1>(Wloc, (size_t)(a * 2 + 1) * 31 + k);
    } else {
        for (int k = 0; k < 31; ++k)
            weff[a * 31 + k] = ldf<0>(Wloc, (size_t)(a * 2) * 31 + k) + ldf<0>(Wloc, (size_t)(a * 2 + 1) * 31 + k);
    }
}

// ---------------- pq = hd @ Wq.T ----------------
template<int F32> __device__ __forceinline__
void pq_body(const float* hd, const void* Wq, float* pq, float* hsh) {  // hsh 1024
    int b = blockIdx.x, a = threadIdx.x;
    for (int idx = a; idx < 1024; idx += 128) hsh[idx] = hd[(size_t)b * DD + idx];
    __syncthreads();
    size_t wr = (size_t)a * 1024;
    float a0 = 0, a1 = 0, a2 = 0, a3 = 0;
    for (int k = 0; k < 1024; k += 16) {
        float4 w, x;
        w = ldf4<F32>(Wq, wr + k);      x = *(const float4*)&hsh[k];      dotf(a0, w, x);
        w = ldf4<F32>(Wq, wr + k + 4);  x = *(const float4*)&hsh[k + 4];  dotf(a1, w, x);
        w = ldf4<F32>(Wq, wr + k + 8);  x = *(const float4*)&hsh[k + 8];  dotf(a2, w, x);
        w = ldf4<F32>(Wq, wr + k + 12); x = *(const float4*)&hsh[k + 12]; dotf(a3, w, x);
    }
    pq[b * AA + a] = (a0 + a1) + (a2 + a3);
}
__global__ __launch_bounds__(128) void k_pq(const float* hd, const void* Wq, float* pq, const int* flag) {
    __shared__ __align__(16) float hsh[1024];
    if (*flag) pq_body<1>(hd, Wq, pq, hsh); else pq_body<0>(hd, Wq, pq, hsh);
}

// ---------------- energies e[b,t'] = v . tanh(pq + pm + pl) ----------------
template<int F32> __device__ __forceinline__
void energy_body(const float* pq, const float* PM, const float* cum, const float* weff,
                 const void* att_v, float* e, float* cumsh, float* part) {  // cumsh 80, part 50*2
    int chunk = blockIdx.x, b = blockIdx.y;
    int t0 = chunk * 50;
    int a = threadIdx.x;
    if (a < 80) {
        int pos = t0 - 15 + a;
        cumsh[a] = (pos >= 0 && pos < TT) ? cum[b * TT + pos] : 0.f;
    }
    float wr[31];
    const float* wp = weff + a * 31;
    #pragma unroll
    for (int k = 0; k < 31; ++k) wr[k] = wp[k];
    float pqv = pq[b * AA + a];
    float vv = ldf<F32>(att_v, a);
    __syncthreads();
    int wid = a >> 6, lane = a & 63;
    for (int tt = 0; tt < 50; ++tt) {
        float acc = pqv + PM[((size_t)(t0 + tt) * BB + b) * AA + a];
        #pragma unroll
        for (int k = 0; k < 31; ++k) acc += wr[k] * cumsh[tt + k];
        float fv = tanhf(acc) * vv;
        #pragma unroll
        for (int m = 1; m < 64; m <<= 1) fv += __shfl_xor(fv, m, 64);
        if (lane == 0) part[tt * 2 + wid] = fv;
    }
    __syncthreads();
    for (int tt = a; tt < 50; tt += 128)
        e[b * TT + t0 + tt] = part[tt * 2 + 0] + part[tt * 2 + 1];
}
__global__ __launch_bounds__(128) void k_energy(const float* pq, const float* PM, const float* cum,
                                                const float* weff, const void* att_v, float* e, const int* flag) {
    __shared__ float cumsh[80];
    __shared__ float part[50 * 2];
    if (*flag) energy_body<1>(pq, PM, cum, weff, att_v, e, cumsh, part);
    else       energy_body<0>(pq, PM, cum, weff, att_v, e, cumsh, part);
}

// ---------------- softmax + cum += align + ctx = align @ memory (fp32 memory) ------
__global__ __launch_bounds__(256) void k_softmax_ctx(const float* e, float* cum, const float* H1, float* ctx) {
    __shared__ float al[400];
    __shared__ float red[256];
    int b = blockIdx.x, tid = threadIdx.x;
    float m = -1e30f;
    for (int t = tid; t < TT; t += 256) { float v = e[b * TT + t]; al[t] = v; m = fmaxf(m, v); }
    red[tid] = m; __syncthreads();
    for (int st = 128; st > 0; st >>= 1) { if (tid < st) red[tid] = fmaxf(red[tid], red[tid + st]); __syncthreads(); }
    m = red[0]; __syncthreads();
    float s = 0.f;
    for (int t = tid; t < TT; t += 256) { float v = __expf(al[t] - m); al[t] = v; s += v; }
    red[tid] = s; __syncthreads();
    for (int st = 128; st > 0; st >>= 1) { if (tid < st) red[tid] += red[tid + st]; __syncthreads(); }
    float inv = 1.0f / red[0];
    __syncthreads();
    for (int t = tid; t < TT; t += 256) { float v = al[t] * inv; al[t] = v; cum[b * TT + t] += v; }
    __syncthreads();
    int d = tid;
    float acc0 = 0.f, acc1 = 0.f;
    for (int t = 0; t < TT; ++t) {
        float a_ = al[t];
        const float* row = H1 + ((size_t)t * BB + b) * EE;
        acc0 += a_ * row[d];
        acc1 += a_ * row[d + 256];
    }
    ctx[b * EE + d] = acc0; ctx[b * EE + d + 256] = acc1;
}

// ---------------- decoder LSTM cell (all fp32; 8-batch x 32-unit tiles) -----------
template<int F32> __device__ __forceinline__
void dec_lstm_body(const float* PRE, const float* ctx, const float* hd_in,
                   const void* Wih, const void* Whh, const void* bbp,
                   float* hd_out, float* cd, int t, float* xs) {  // xs 8*1800
    int u0 = (blockIdx.x >> 4) * 32;
    int b0 = (blockIdx.x & 15) * 8;
    int tid = threadIdx.x;
    for (int idx = tid; idx < 8 * 1792; idx += 256) {
        int bi2 = idx / 1792, k = idx - bi2 * 1792;
        int bidx = b0 + bi2;
        float v;
        if (k < 256)      v = PRE[((size_t)t * BB + bidx) * HH + k];
        else if (k < 768) v = ctx[(size_t)bidx * EE + (k - 256)];
        else              v = hd_in[(size_t)bidx * DD + (k - 768)];
        xs[bi2 * 1800 + k] = v;
    }
    __syncthreads();
    int bi = tid >> 5, ui = tid & 31;
    int b = b0 + bi, u = u0 + ui;
    float ai = ldf<F32>(bbp, u), af = ldf<F32>(bbp, u + 1024);
    float ag = ldf<F32>(bbp, u + 2048), ao = ldf<F32>(bbp, u + 3072);
    const float* xp = xs + bi * 1800;
    {
        size_t wi = (size_t)u * 768, wf = (size_t)(u + 1024) * 768;
        size_t wg = (size_t)(u + 2048) * 768, wo = (size_t)(u + 3072) * 768;
        for (int k = 0; k < 768; k += 4) {
            float4 x = *(const float4*)(xp + k);
            float4 w;
            w = ldf4<F32>(Wih, wi + k); dotf(ai, w, x);
            w = ldf4<F32>(Wih, wf + k); dotf(af, w, x);
            w = ldf4<F32>(Wih, wg + k); dotf(ag, w, x);
            w = ldf4<F32>(Wih, wo + k); dotf(ao, w, x);
        }
    }
    {
        const float* xh = xp + 768;
        size_t wi = (size_t)u * 1024, wf = (size_t)(u + 1024) * 1024;
        size_t wg = (size_t)(u + 2048) * 1024, wo = (size_t)(u + 3072) * 1024;
        for (int k = 0; k < 1024; k += 4) {
            float4 x = *(const float4*)(xh + k);
            float4 w;
            w = ldf4<F32>(Whh, wi + k); dotf(ai, w, x);
            w = ldf4<F32>(Whh, wf + k); dotf(af, w, x);
            w = ldf4<F32>(Whh, wg + k); dotf(ag, w, x);
            w = ldf4<F32>(Whh, wo + k); dotf(ao, w, x);
        }
    }
    float iv = sigm(ai), fv = sigm(af), gv = tanhf(ag), ov = sigm(ao);
    float c = cd[(size_t)b * DD + u];
    c = fv * c + iv * gv;
    cd[(size_t)b * DD + u] = c;
    hd_out[(size_t)b * DD + u] = ov * tanhf(c);
}
__global__ __launch_bounds__(256) void k_dec_lstm(const float* PRE, const float* ctx, const float* hd_in,
                                                  const void* Wih, const void* Whh, const void* bbp,
                                                  float* hd_out, float* cd, int t, const int* flag) {
    __shared__ __align__(16) float xs[8 * 1800];  // stride 1800 to dodge bank conflicts
    if (*flag) dec_lstm_body<1>(PRE, ctx, hd_in, Wih, Whh, bbp, hd_out, cd, t, xs);
    else       dec_lstm_body<0>(PRE, ctx, hd_in, Wih, Whh, bbp, hd_out, cd, t, xs);
}

// ---------------- output projection + gate ----------------
template<int F32> __device__ __forceinline__
void dec_out_body(const float* hd, const float* ctx, const void* outW, const void* outB,
                  void* dout, int t, float* xsh) {  // xsh 1536
    int b = blockIdx.x, tid = threadIdx.x;
    for (int idx = tid; idx < 1536; idx += 256)
        xsh[idx] = (idx < 1024) ? hd[(size_t)b * DD + idx] : ctx[(size_t)b * EE + (idx - 1024)];
    __syncthreads();
    if (tid < 240) {
        size_t wr = (size_t)tid * 1536;
        float a0 = 0, a1 = 0, a2 = 0, a3 = 0;
        for (int k = 0; k < 1536; k += 16) {
            float4 w, x;
            w = ldf4<F32>(outW, wr + k);      x = *(const float4*)&xsh[k];      dotf(a0, w, x);
            w = ldf4<F32>(outW, wr + k + 4);  x = *(const float4*)&xsh[k + 4];  dotf(a1, w, x);
            w = ldf4<F32>(outW, wr + k + 8);  x = *(const float4*)&xsh[k + 8];  dotf(a2, w, x);
            w = ldf4<F32>(outW, wr + k + 12); x = *(const float4*)&xsh[k + 12]; dotf(a3, w, x);
        }
        float acc = ldf<F32>(outB, tid) + ((a0 + a1) + (a2 + a3));
        int j = tid / 80, mm = tid - j * 80;
        int col = 3 * t + j;
        stf<F32>(dout, (size_t)b * 96000 + (size_t)mm * 1200 + col, acc);                   // mel_outputs
        if (mm == 79) stf<F32>(dout, (size_t)24576000 + (size_t)b * 1200 + col, sigm(acc)); // gate
    }
}
__global__ __launch_bounds__(256) void k_dec_out(const float* hd, const float* ctx, const void* outW,
                                                 const void* outB, void* dout, int t, const int* flag) {
    __shared__ __align__(16) float xsh[1536];
    if (*flag) dec_out_body<1>(hd, ctx, outW, outB, dout, t, xsh);
    else       dec_out_body<0>(hd, ctx, outW, outB, dout, t, xsh);
}

// ---------------- postnet conv1 (80->512, k5 pad2) + bias; P1 bf16 (small err) -----
template<int F32> __device__ __forceinline__
void post1_body(const void* dout, const void* W, const void* bias, u16* P1, u16* msh) {  // msh 80*68
    int t0 = blockIdx.x * 64, o0 = blockIdx.y * 32, b = blockIdx.z;
    int tid = threadIdx.x;
    for (int idx = tid; idx < 80 * 68; idx += 256) {
        int i = idx / 68, rest = idx - i * 68;
        int t = t0 - 2 + rest;
        u16 v = 0;
        if (t >= 0 && t < T3) v = f2b(ldf<F32>(dout, (size_t)b * 96000 + (size_t)i * 1200 + t));
        msh[idx] = v;
    }
    __syncthreads();
    int ol = tid >> 3, tg = tid & 7;
    int o = o0 + ol, tl = tg * 8;
    float acc[8];
    float bv = ldf<F32>(bias, o);
    #pragma unroll
    for (int j = 0; j < 8; ++j) acc[j] = bv;
    size_t wrow = (size_t)o * 400;
    for (int i = 0; i < 80; ++i) {
        float xv[12];
        #pragma unroll
        for (int j = 0; j < 12; ++j) xv[j] = b2f(msh[i * 68 + tl + j]);
        #pragma unroll
        for (int k = 0; k < 5; ++k) {
            float w = ldf<F32>(W, wrow + i * 5 + k);
            #pragma unroll
            for (int j = 0; j < 8; ++j) acc[j] += w * xv[j + k];
        }
    }
    #pragma unroll
    for (int j = 0; j < 8; ++j) {
        int t = t0 + tl + j;
        if (t < T3) P1[((size_t)b * EE + o) * T3 + t] = f2b(acc[j]);
    }
}
__global__ __launch_bounds__(256) void k_post1(const void* dout, const void* W, const void* bias,
                                               u16* P1, const int* flag) {
    __shared__ u16 msh[80 * 68];
    if (*flag) post1_body<1>(dout, W, bias, P1, msh); else post1_body<0>(dout, W, bias, P1, msh);
}

// ---------------- postnet conv2 (512->80) over tanh(BN(P1)), + residual ----------
template<int F32> __device__ __forceinline__
void post2_body(const u16* P1, const float* mu, const float* rs, const void* g, const void* beta,
                const void* W2, const void* b2v, void* dout, float* tsh) {  // tsh 128*37
    int t0 = blockIdx.x * 32, b = blockIdx.y;
    int tid = threadIdx.x;
    int tl = tid >> 3, mg = tid & 7;
    float acc[10];
    #pragma unroll
    for (int q = 0; q < 10; ++q) acc[q] = ldf<F32>(b2v, mg + 8 * q);
    for (int oc = 0; oc < 4; ++oc) {
        int o0 = oc * 128;
        __syncthreads();
        for (int idx = tid; idx < 128 * 36; idx += 256) {
            int i = idx / 36, rest = idx - i * 36;
            int t = t0 - 2 + rest;
            float v = 0.f;
            if (t >= 0 && t < T3) {
                int o = o0 + i;
                float raw = b2f(P1[((size_t)b * EE + o) * T3 + t]);
                v = tanhf((raw - mu[o]) * rs[o] * ldf<F32>(g, o) + ldf<F32>(beta, o));
            }
            tsh[i * 37 + rest] = v;
        }
        __syncthreads();
        for (int i = 0; i < 128; ++i) {
            float xv[5];
            #pragma unroll
            for (int k = 0; k < 5; ++k) xv[k] = tsh[i * 37 + tl + k];
            #pragma unroll
            for (int q = 0; q < 10; ++q) {
                int m = mg + 8 * q;
                size_t wp = ((size_t)m * 512 + o0 + i) * 5;
                acc[q] += ldf<F32>(W2, wp + 0) * xv[0];
                acc[q] += ldf<F32>(W2, wp + 1) * xv[1];
                acc[q] += ldf<F32>(W2, wp + 2) * xv[2];
                acc[q] += ldf<F32>(W2, wp + 3) * xv[3];
                acc[q] += ldf<F32>(W2, wp + 4) * xv[4];
            }
        }
    }
    int t = t0 + tl;
    if (t < T3) {
        #pragma unroll
        for (int q = 0; q < 10; ++q) {
            int m = mg + 8 * q;
            size_t idx = (size_t)b * 96000 + (size_t)m * 1200 + t;
            float res = ldf<F32>(dout, idx);                       // mel_outputs residual
            stf<F32>(dout, (size_t)12288000 + idx, acc[q] + res);  // mel_postnet
        }
    }
}
__global__ __launch_bounds__(256) void k_post2(const u16* P1, const float* mu, const float* rs,
                                               const void* g, const void* beta, const void* W2,
                                               const void* b2v, void* dout, const int* flag) {
    __shared__ float tsh[128 * 37];
    if (*flag) post2_body<1>(P1, mu, rs, g, beta, W2, b2v, dout, tsh);
    else       post2_body<0>(P1, mu, rs, g, beta, W2, b2v, dout, tsh);
}

extern "C" void kernel_launch(void* const* d_in, const int* in_sizes, int n_in,
                              void* d_out, int out_size, void* d_ws, size_t ws_size,
                              hipStream_t stream) {
    const int*  text       = (const int*)d_in[0];
    const void* mels       = d_in[1];
    const void* emb        = d_in[2];
    const void* enc_conv_w = d_in[3];
    const void* enc_conv_b = d_in[4];
    const void* bn_g       = d_in[5];
    const void* bn_b       = d_in[6];
    const void* lstm_Wih   = d_in[7];
    const void* lstm_Whh   = d_in[8];
    const void* lstm_b     = d_in[9];
    const void* pre_W1     = d_in[10];
    const void* pre_b1     = d_in[11];
    const void* pre_W2     = d_in[12];
    const void* pre_b2     = d_in[13];
    const void* att_Wq     = d_in[14];
    const void* att_Wm     = d_in[15];
    const void* att_Wloc   = d_in[16];
    const void* att_v      = d_in[17];
    const void* dec_Wih    = d_in[18];
    const void* dec_Whh    = d_in[19];
    const void* dec_b      = d_in[20];
    const void* out_W      = d_in[21];
    const void* out_b      = d_in[22];
    const void* post_w1    = d_in[23];
    const void* post_b1    = d_in[24];
    const void* post_g     = d_in[25];
    const void* post_bta   = d_in[26];
    const void* post_w2    = d_in[27];
    const void* post_b2    = d_in[28];

    const size_t WS_NEED = 212049924;
    if (ws_size < WS_NEED) {
        fprintf(stderr, "kernel_launch: ws_size %zu < needed %zu\n", ws_size, WS_NEED);
        return;
    }
    // Two 104.86MB fp32 slots, ping-pong:
    //  S0=[0,104857600)  S1=[104857600,209715200)
    //  X fp32 (S0, full slot) -> Y(S1) -> H0(S0) -> A(S1) -> B(S0) -> memory H1f(S1)
    //  then PM+PRE in S0; postnet P1(u16,157MB) at [0,157286400)
    char* ws = (char*)d_ws;
    float* X    = (float*)(ws + 0);           // 128*512*400*4 = 104857600 exactly
    float* Yf   = (float*)(ws + 104857600);
    float* H0f  = (float*)(ws + 0);
    float* Af   = (float*)(ws + 104857600);
    float* Bf   = (float*)(ws + 0);
    float* H1f  = (float*)(ws + 104857600);   // memory (fp32), live through decoder
    float* PM   = (float*)(ws + 0);           // 26214400 B
    float* PRE  = (float*)(ws + 26214400);    // 52428800 B
    u16*   P1   = (u16*)(ws + 0);             // postnet, 157286400 B (H1f/PM/PRE dead)
    char* SM = ws + 209715200;
    float* weff  = (float*)(SM + 0);
    float* encmu = (float*)(SM + 16384);
    float* encrs = (float*)(SM + 18432);
    float* pmu   = (float*)(SM + 20480);
    float* prs   = (float*)(SM + 22528);
    float* pq    = (float*)(SM + 24576);
    float* ebuf  = (float*)(SM + 90112);
    float* cum   = (float*)(SM + 294912);
    float* ctx   = (float*)(SM + 499712);
    float* hd0   = (float*)(SM + 761856);
    float* hd1   = (float*)(SM + 1286144);
    float* cd    = (float*)(SM + 1810432);
    int*   flag  = (int*)(SM + 2334720);

    k_detect<<<1, 256, 0, stream>>>(emb, flag);
    hipMemsetAsync(SM, 0, 2334720, stream);
    k_weff<<<1, 128, 0, stream>>>(att_Wloc, weff, flag);

    // ---- encoder ----
    k_embed<<<dim3(512, 128), 256, 0, stream>>>(text, emb, X, flag);
    k_encconv<<<dim3(7, 16, 128), 256, 0, stream>>>(X, enc_conv_w, enc_conv_b, Yf, flag);
    k_bnstats<<<512, 256, 0, stream>>>(Yf, encmu, encrs, 400, 512, 128, 1);
    k_bnapply<<<dim3(7, 8, 128), 256, 0, stream>>>(Yf, encmu, encrs, bn_g, bn_b, H0f, flag);
    k_lstm<<<128, 256, 0, stream>>>(H0f, Af, lstm_Wih, lstm_Whh, lstm_b, 0, flag);
    k_lstm<<<128, 256, 0, stream>>>(Af, Bf, lstm_Wih, lstm_Whh, lstm_b, 1, flag);
    k_lstm<<<128, 256, 0, stream>>>(Bf, H1f, lstm_Wih, lstm_Whh, lstm_b, 2, flag);

    // ---- decoder precompute ----
    k_pm<<<dim3(50, 128), 128, 0, stream>>>(H1f, att_Wm, PM, flag);
    k_prenet<<<dim3(8, 400), 256, 0, stream>>>(mels, pre_W1, pre_b1, pre_W2, pre_b2, PRE, flag);

    // ---- decoder scan ----
    for (int t = 0; t < TT; ++t) {
        float* hin  = (t & 1) ? hd1 : hd0;
        float* hout = (t & 1) ? hd0 : hd1;
        k_pq<<<128, 128, 0, stream>>>(hin, att_Wq, pq, flag);
        k_energy<<<dim3(8, 128), 128, 0, stream>>>(pq, PM, cum, weff, att_v, ebuf, flag);
        k_softmax_ctx<<<128, 256, 0, stream>>>(ebuf, cum, H1f, ctx);
        k_dec_lstm<<<512, 256, 0, stream>>>(PRE, ctx, hin, dec_Wih, dec_Whh, dec_b, hout, cd, t, flag);
        k_dec_out<<<128, 256, 0, stream>>>(hout, ctx, out_W, out_b, d_out, t, flag);
    }

    // ---- postnet ----
    k_post1<<<dim3(19, 16, 128), 256, 0, stream>>>(d_out, post_w1, post_b1, P1, flag);
    k_bnstats<<<512, 256, 0, stream>>>(P1, pmu, prs, 1200, 512, 128, 0);
    k_post2<<<dim3(38, 128), 256, 0, stream>>>(P1, pmu, prs, post_g, post_bta, post_w2, post_b2, d_out, flag);
}

// Round 6
// 173932.483 us; speedup vs baseline: 2.0398x; 2.0398x over previous
//
#include <hip/hip_runtime.h>
#include <cstdio>
#include <cstddef>

typedef unsigned short u16;
typedef unsigned int u32;

#define BB   128
#define TT   400
#define EE   512
#define HH   256
#define NMEL 80
#define AA   128
#define DD   1024
#define T3   1200

__device__ __forceinline__ float b2f(u16 h) { return __uint_as_float(((u32)h) << 16); }
__device__ __forceinline__ u16 f2b(float f) {
    u32 x = __float_as_uint(f);
    u32 r = (x + 0x7FFFu + ((x >> 16) & 1u)) >> 16;
    return (u16)r;
}
__device__ __forceinline__ float sigm(float x) { return 1.0f / (1.0f + __expf(-x)); }

// dual-dtype EXTERNAL-input loads (F32=1: buffer is float32; F32=0: bf16 u16)
template<int F32> __device__ __forceinline__ float ldf(const void* p, size_t i) {
    if (F32) return ((const float*)p)[i];
    return b2f(((const u16*)p)[i]);
}
template<int F32> __device__ __forceinline__ float4 ldf4(const void* p, size_t i) {
    if (F32) return *(const float4*)((const float*)p + i);
    ushort4 w = *(const ushort4*)((const u16*)p + i);
    return make_float4(b2f(w.x), b2f(w.y), b2f(w.z), b2f(w.w));
}
template<int F32> __device__ __forceinline__ void stf(void* p, size_t i, float v) {
    if (F32) ((float*)p)[i] = v;
    else ((u16*)p)[i] = f2b(v);
}
__device__ __forceinline__ void dotf(float& a, float4 w, float4 x) {
    a += w.x * x.x; a += w.y * x.y; a += w.z * x.z; a += w.w * x.w;
}

// ---------------- dtype detector (probe emb) ----------------
__global__ __launch_bounds__(256) void k_detect(const void* emb, int* flag) {
    int tid = threadIdx.x;
    const u16* p = (const u16*)emb;
    int insane = 0;
    for (int i = tid; i < 4096; i += 256) {
        u16 h = p[2 * i];
        u32 ex = (h >> 7) & 0xFF;
        if (ex < 96 || ex > 159) insane++;
    }
    __shared__ int red[256];
    red[tid] = insane; __syncthreads();
    for (int st = 128; st > 0; st >>= 1) {
        if (tid < st) red[tid] += red[tid + st];
        __syncthreads();
    }
    if (tid == 0) *flag = (red[0] > 1024) ? 1 : 0;
}

// ---------------- embedding: X[b,e,t] = emb[text[b,t], e]  (fp32 staging) ------
template<int F32> __device__ __forceinline__ void embed_body(const int* text, const void* emb, float* X) {
    int e = blockIdx.x, b = blockIdx.y;
    for (int t = threadIdx.x; t < TT; t += 256) {
        int v = text[b * TT + t];
        X[((size_t)b * EE + e) * TT + t] = ldf<F32>(emb, (size_t)v * EE + e);
    }
}
__global__ __launch_bounds__(256) void k_embed(const int* text, const void* emb, float* X, const int* flag) {
    if (*flag) embed_body<1>(text, emb, X); else embed_body<0>(text, emb, X);
}

// ---------------- encoder conv5 pad2 + bias + relu -> fp32 Y ----------------
template<int F32> __device__ __forceinline__
void encconv_body(const float* X, const void* W, const void* bias, float* Y, float* xs) {
    int t0 = blockIdx.x * 64, o0 = blockIdx.y * 32, b = blockIdx.z;
    int tid = threadIdx.x;
    int ol = tid >> 3, tg = tid & 7;
    int o = o0 + ol, tl = tg * 8;
    float acc[8];
    float bv = ldf<F32>(bias, o);
    #pragma unroll
    for (int j = 0; j < 8; ++j) acc[j] = bv;
    for (int q = 0; q < 4; ++q) {
        __syncthreads();
        for (int idx = tid; idx < 128 * 68; idx += 256) {
            int il = idx / 68, rest = idx - il * 68;
            int t = t0 - 2 + rest;
            float v = 0.f;
            if (t >= 0 && t < TT) v = X[((size_t)b * EE + q * 128 + il) * TT + t];
            xs[idx] = v;
        }
        __syncthreads();
        size_t wbase = ((size_t)o * EE + q * 128) * 5;
        for (int il = 0; il < 128; ++il) {
            float xv[12];
            #pragma unroll
            for (int j = 0; j < 12; ++j) xv[j] = xs[il * 68 + tl + j];
            #pragma unroll
            for (int k = 0; k < 5; ++k) {
                float w = ldf<F32>(W, wbase + il * 5 + k);
                #pragma unroll
                for (int j = 0; j < 8; ++j) acc[j] += w * xv[j + k];
            }
        }
    }
    #pragma unroll
    for (int j = 0; j < 8; ++j) {
        int t = t0 + tl + j;
        if (t < TT) Y[((size_t)b * EE + o) * TT + t] = acc[j] > 0.f ? acc[j] : 0.f;
    }
}
__global__ __launch_bounds__(256) void k_encconv(const float* X, const void* W, const void* bias, float* Y, const int* flag) {
    __shared__ float xs[128 * 68];
    if (*flag) encconv_body<1>(X, W, bias, Y, xs); else encconv_body<0>(X, W, bias, Y, xs);
}

// ---------------- BatchNorm stats (train mode, biased var) ----
template<int INF32> __device__ __forceinline__
void bnstats_body(const void* Y, float* mu, float* rs, int L, int C, int Bn) {
    int o = blockIdx.x, tid = threadIdx.x;
    float s = 0.f, s2 = 0.f;
    for (int b = 0; b < Bn; ++b) {
        size_t base = ((size_t)b * C + o) * L;
        for (int t = tid; t < L; t += 256) {
            float v = INF32 ? ((const float*)Y)[base + t] : b2f(((const u16*)Y)[base + t]);
            s += v; s2 += v * v;
        }
    }
    __shared__ float r1[256], r2[256];
    r1[tid] = s; r2[tid] = s2; __syncthreads();
    for (int st = 128; st > 0; st >>= 1) {
        if (tid < st) { r1[tid] += r1[tid + st]; r2[tid] += r2[tid + st]; }
        __syncthreads();
    }
    if (tid == 0) {
        float n = (float)Bn * (float)L;
        float m = r1[0] / n;
        float var = r2[0] / n - m * m;
        mu[o] = m;
        rs[o] = 1.0f / sqrtf(var + 1e-5f);
    }
}
__global__ __launch_bounds__(256) void k_bnstats(const void* Y, float* mu, float* rs, int L, int C, int Bn, int inf32) {
    if (inf32) bnstats_body<1>(Y, mu, rs, L, C, Bn); else bnstats_body<0>(Y, mu, rs, L, C, Bn);
}

// ---------------- BN apply + transpose [B,C,T] -> [T,B,C], fp32->fp32 ----------------
template<int F32> __device__ __forceinline__
void bnapply_body(const float* Y, const float* mu, const float* rs, const void* g, const void* beta,
                  float* H, float* tile) {
    int t0 = blockIdx.x * 64, c0 = blockIdx.y * 64, b = blockIdx.z;
    int tid = threadIdx.x;
    for (int idx = tid; idx < 64 * 64; idx += 256) {
        int cl = idx >> 6, tl = idx & 63;
        int t = t0 + tl, c = c0 + cl;
        float v = 0.f;
        if (t < TT) v = Y[((size_t)b * EE + c) * TT + t];
        tile[cl * 65 + tl] = (v - mu[c]) * rs[c] * ldf<F32>(g, c) + ldf<F32>(beta, c);
    }
    __syncthreads();
    for (int idx = tid; idx < 64 * 64; idx += 256) {
        int tl = idx >> 6, cl = idx & 63;
        int t = t0 + tl;
        if (t < TT) H[((size_t)t * BB + b) * EE + c0 + cl] = tile[cl * 65 + tl];
    }
}
__global__ __launch_bounds__(256) void k_bnapply(const float* Y, const float* mu, const float* rs,
                                                 const void* g, const void* beta, float* H, const int* flag) {
    __shared__ float tile[64 * 65];
    if (*flag) bnapply_body<1>(Y, mu, rs, g, beta, H, tile); else bnapply_body<0>(Y, mu, rs, g, beta, H, tile);
}

// ---------------- encoder weight transpose: WtE[ld][k][u].{i,f,g,o} ----------------
// k<512 from Wih[ld][g*256+u][k]; k>=512 from Whh[ld][g*256+u][k-512]
template<int F32> __device__ __forceinline__
void transEnc_body(const void* Wih, const void* Whh, float* WtE) {
    int ld = blockIdx.x;        // 0..5
    int k  = blockIdx.y;        // 0..767
    int u  = threadIdx.x;       // 0..255
    float4 w;
    if (k < 512) {
        size_t base = (size_t)ld * 1024 * 512;
        w.x = ldf<F32>(Wih, base + (size_t)(u)       * 512 + k);
        w.y = ldf<F32>(Wih, base + (size_t)(256 + u) * 512 + k);
        w.z = ldf<F32>(Wih, base + (size_t)(512 + u) * 512 + k);
        w.w = ldf<F32>(Wih, base + (size_t)(768 + u) * 512 + k);
    } else {
        size_t base = (size_t)ld * 1024 * 256;
        int kk = k - 512;
        w.x = ldf<F32>(Whh, base + (size_t)(u)       * 256 + kk);
        w.y = ldf<F32>(Whh, base + (size_t)(256 + u) * 256 + kk);
        w.z = ldf<F32>(Whh, base + (size_t)(512 + u) * 256 + kk);
        w.w = ldf<F32>(Whh, base + (size_t)(768 + u) * 256 + kk);
    }
    ((float4*)WtE)[((size_t)ld * 768 + k) * 256 + u] = w;
}
__global__ __launch_bounds__(256) void k_transEnc(const void* Wih, const void* Whh, float* WtE, const int* flag) {
    if (*flag) transEnc_body<1>(Wih, Whh, WtE); else transEnc_body<0>(Wih, Whh, WtE);
}

// ---------------- one biLSTM layer, coalesced weights (WtE), 2 batch rows/block ---
template<int F32> __device__ __forceinline__
void lstm2_body(const float* Hin, float* Hout, const float* WtE, const void* b_all, int layer,
                float* xsh, float* hsh) {
    int d = blockIdx.x >> 6;            // 0 fwd, 1 bwd
    int b0 = (blockIdx.x & 63) * 2;
    int u = threadIdx.x;                // hidden unit 0..255
    int ld = layer * 2 + d;
    size_t bB = (size_t)ld * 1024;
    float bi_ = ldf<F32>(b_all, bB + u),       bf_ = ldf<F32>(b_all, bB + 256 + u);
    float bg_ = ldf<F32>(b_all, bB + 512 + u), bo_ = ldf<F32>(b_all, bB + 768 + u);
    const float4* W4 = (const float4*)WtE + (size_t)ld * 768 * 256 + u;
    float c0v = 0.f, c1v = 0.f;
    hsh[u] = 0.f; hsh[256 + u] = 0.f;
    for (int s = 0; s < TT; ++s) {
        int t = d ? (TT - 1 - s) : s;
        __syncthreads();
        const float* src = Hin + ((size_t)t * BB + b0) * EE;
        xsh[u] = src[u];             xsh[256 + u] = src[256 + u];
        xsh[512 + u] = src[512 + u]; xsh[768 + u] = src[768 + u];
        __syncthreads();
        float a0i = bi_, a0f = bf_, a0g = bg_, a0o = bo_;
        float a1i = bi_, a1f = bf_, a1g = bg_, a1o = bo_;
        #pragma unroll 8
        for (int k = 0; k < 512; ++k) {
            float4 w = W4[(size_t)k * 256];
            float x0 = xsh[k], x1 = xsh[512 + k];
            a0i += w.x * x0; a0f += w.y * x0; a0g += w.z * x0; a0o += w.w * x0;
            a1i += w.x * x1; a1f += w.y * x1; a1g += w.z * x1; a1o += w.w * x1;
        }
        #pragma unroll 8
        for (int k = 0; k < 256; ++k) {
            float4 w = W4[(size_t)(512 + k) * 256];
            float h0 = hsh[k], h1 = hsh[256 + k];
            a0i += w.x * h0; a0f += w.y * h0; a0g += w.z * h0; a0o += w.w * h0;
            a1i += w.x * h1; a1f += w.y * h1; a1g += w.z * h1; a1o += w.w * h1;
        }
        float i0 = sigm(a0i), f0 = sigm(a0f), g0 = tanhf(a0g), o0v = sigm(a0o);
        c0v = f0 * c0v + i0 * g0;
        float h0v = o0v * tanhf(c0v);
        float i1 = sigm(a1i), f1 = sigm(a1f), g1 = tanhf(a1g), o1v = sigm(a1o);
        c1v = f1 * c1v + i1 * g1;
        float h1v = o1v * tanhf(c1v);
        __syncthreads();
        hsh[u] = h0v; hsh[256 + u] = h1v;
        Hout[((size_t)t * BB + b0) * EE + d * HH + u]     = h0v;
        Hout[((size_t)t * BB + b0 + 1) * EE + d * HH + u] = h1v;
    }
}
__global__ __launch_bounds__(256) void k_lstm2(const float* Hin, float* Hout, const float* WtE,
                                               const void* bb, int layer, const int* flag) {
    __shared__ __align__(16) float xsh[1024];
    __shared__ __align__(16) float hsh[512];
    if (*flag) lstm2_body<1>(Hin, Hout, WtE, bb, layer, xsh, hsh);
    else       lstm2_body<0>(Hin, Hout, WtE, bb, layer, xsh, hsh);
}

// ---------------- pm[t,b,a] = memory[b,t,:] . Wm[a,:]  (one-shot) ----------------
template<int F32> __device__ __forceinline__
void pm_body(const float* H1, const void* Wm, float* PM, float* xsh) {
    int t0 = blockIdx.x * 8, b = blockIdx.y;
    int tid = threadIdx.x;
    for (int idx = tid; idx < 8 * 512; idx += 128) {
        int tt = idx >> 9, k = idx & 511;
        xsh[tt * 512 + k] = H1[((size_t)(t0 + tt) * BB + b) * EE + k];
    }
    __syncthreads();
    size_t wrow = (size_t)tid * 512;
    float acc[8] = {0, 0, 0, 0, 0, 0, 0, 0};
    for (int k = 0; k < 512; k += 4) {
        float4 w = ldf4<F32>(Wm, wrow + k);
        #pragma unroll
        for (int tt = 0; tt < 8; ++tt) {
            float4 x = *(const float4*)&xsh[tt * 512 + k];
            acc[tt] += w.x * x.x; acc[tt] += w.y * x.y; acc[tt] += w.z * x.z; acc[tt] += w.w * x.w;
        }
    }
    #pragma unroll
    for (int tt = 0; tt < 8; ++tt)
        PM[((size_t)(t0 + tt) * BB + b) * AA + tid] = acc[tt];
}
__global__ __launch_bounds__(128) void k_pm(const float* H1, const void* Wm, float* PM, const int* flag) {
    __shared__ __align__(16) float xsh[8 * 512];
    if (*flag) pm_body<1>(H1, Wm, PM, xsh); else pm_body<0>(H1, Wm, PM, xsh);
}

// ---------------- per-step prenet (fp32): PRE_t[b][j] ----------------
template<int F32> __device__ __forceinline__
void prenet_step_body(const void* mels, const void* W1, const void* b1, const void* W2, const void* b2,
                      float* PRE_t, int t, float* melsh, float* h1) {
    int b = blockIdx.x, j = threadIdx.x;
    if (j < 80) melsh[j] = (t == 0) ? 0.f : ldf<F32>(mels, ((size_t)b * NMEL + j) * TT + (t - 1));
    __syncthreads();
    float a = ldf<F32>(b1, j);
    for (int m = 0; m < 80; ++m) a += ldf<F32>(W1, (size_t)j * 80 + m) * melsh[m];
    h1[j] = a > 0.f ? a : 0.f;
    __syncthreads();
    float a2 = ldf<F32>(b2, j);
    for (int k = 0; k < 256; k += 4) {
        float4 w = ldf4<F32>(W2, (size_t)j * 256 + k);
        a2 += w.x * h1[k] + w.y * h1[k + 1] + w.z * h1[k + 2] + w.w * h1[k + 3];
    }
    PRE_t[(size_t)b * HH + j] = a2 > 0.f ? a2 : 0.f;
}
__global__ __launch_bounds__(256) void k_prenet_step(const void* mels, const void* W1, const void* b1,
                                                     const void* W2, const void* b2, float* PRE_t,
                                                     int t, const int* flag) {
    __shared__ float melsh[80];
    __shared__ float h1[256];
    if (*flag) prenet_step_body<1>(mels, W1, b1, W2, b2, PRE_t, t, melsh, h1);
    else       prenet_step_body<0>(mels, W1, b1, W2, b2, PRE_t, t, melsh, h1);
}

// ---------------- effective 1-channel location kernel ----------------
__global__ void k_weff(const void* Wloc, float* weff, const int* flag) {
    int a = threadIdx.x;
    if (*flag) {
        for (int k = 0; k < 31; ++k)
            weff[a * 31 + k] = ldf<1>(Wloc, (size_t)(a * 2) * 31 + k) + ldf<1>(Wloc, (size_t)(a * 2 + 1) * 31 + k);
    } else {
        for (int k = 0; k < 31; ++k)
            weff[a * 31 + k] = ldf<0>(Wloc, (size_t)(a * 2) * 31 + k) + ldf<0>(Wloc, (size_t)(a * 2 + 1) * 31 + k);
    }
}

// ---------------- decoder weight transposes (one-time) ----------------
template<int F32> __device__ __forceinline__
void transW_body(const void* Wih, const void* Whh, float* Wt2) {
    int u = blockIdx.x * 256 + threadIdx.x;   // 0..1023
    int k = blockIdx.y;                       // 0..1791
    float4 w;
    if (k < 768) {
        w.x = ldf<F32>(Wih, (size_t)(0 * 1024 + u) * 768 + k);
        w.y = ldf<F32>(Wih, (size_t)(1 * 1024 + u) * 768 + k);
        w.z = ldf<F32>(Wih, (size_t)(2 * 1024 + u) * 768 + k);
        w.w = ldf<F32>(Wih, (size_t)(3 * 1024 + u) * 768 + k);
    } else {
        int kk = k - 768;
        w.x = ldf<F32>(Whh, (size_t)(0 * 1024 + u) * 1024 + kk);
        w.y = ldf<F32>(Whh, (size_t)(1 * 1024 + u) * 1024 + kk);
        w.z = ldf<F32>(Whh, (size_t)(2 * 1024 + u) * 1024 + kk);
        w.w = ldf<F32>(Whh, (size_t)(3 * 1024 + u) * 1024 + kk);
    }
    ((float4*)Wt2)[(size_t)k * 1024 + u] = w;
}
__global__ __launch_bounds__(256) void k_transW(const void* Wih, const void* Whh, float* Wt2, const int* flag) {
    if (*flag) transW_body<1>(Wih, Whh, Wt2); else transW_body<0>(Wih, Whh, Wt2);
}

__global__ __launch_bounds__(256) void k_transOut(const void* outW, float* outWt, const int* flag) {
    int k = blockIdx.x;            // 0..1535
    int j = threadIdx.x;           // active < 240
    if (j < 240) {
        float v = (*flag) ? ldf<1>(outW, (size_t)j * 1536 + k) : ldf<0>(outW, (size_t)j * 1536 + k);
        outWt[(size_t)k * 240 + j] = v;
    }
}
__global__ __launch_bounds__(128) void k_transWq(const void* Wq, float* Wqt, const int* flag) {
    int k = blockIdx.x;            // 0..1023
    int a = threadIdx.x;           // 0..127
    float v = (*flag) ? ldf<1>(Wq, (size_t)a * 1024 + k) : ldf<0>(Wq, (size_t)a * 1024 + k);
    Wqt[(size_t)k * AA + a] = v;
}

// ---------------- pq = hd @ Wq.T  (coalesced via Wqt[k][a]) ----------------
__global__ __launch_bounds__(128) void k_pq2(const float* hd, const float* Wqt, float* pq) {
    __shared__ __align__(16) float hsh[1024];
    int b = blockIdx.x, a = threadIdx.x;
    for (int idx = a; idx < 1024; idx += 128) hsh[idx] = hd[(size_t)b * DD + idx];
    __syncthreads();
    float a0 = 0, a1 = 0, a2 = 0, a3 = 0;
    for (int k = 0; k < 1024; k += 4) {
        a0 += Wqt[(size_t)(k + 0) * AA + a] * hsh[k + 0];
        a1 += Wqt[(size_t)(k + 1) * AA + a] * hsh[k + 1];
        a2 += Wqt[(size_t)(k + 2) * AA + a] * hsh[k + 2];
        a3 += Wqt[(size_t)(k + 3) * AA + a] * hsh[k + 3];
    }
    pq[b * AA + a] = (a0 + a1) + (a2 + a3);
}

// ---------------- energies e[b,t'] = v . tanh(pq + pm + pl) ----------------
template<int F32> __device__ __forceinline__
void energy_body(const float* pq, const float* PM, const float* cum, const float* weff,
                 const void* att_v, float* e, float* cumsh, float* part) {
    int chunk = blockIdx.x, b = blockIdx.y;
    int t0 = chunk * 50;
    int a = threadIdx.x;
    if (a < 80) {
        int pos = t0 - 15 + a;
        cumsh[a] = (pos >= 0 && pos < TT) ? cum[b * TT + pos] : 0.f;
    }
    float wr[31];
    const float* wp = weff + a * 31;
    #pragma unroll
    for (int k = 0; k < 31; ++k) wr[k] = wp[k];
    float pqv = pq[b * AA + a];
    float vv = ldf<F32>(att_v, a);
    __syncthreads();
    int wid = a >> 6, lane = a & 63;
    for (int tt = 0; tt < 50; ++tt) {
        float acc = pqv + PM[((size_t)(t0 + tt) * BB + b) * AA + a];
        #pragma unroll
        for (int k = 0; k < 31; ++k) acc += wr[k] * cumsh[tt + k];
        float fv = tanhf(acc) * vv;
        #pragma unroll
        for (int m = 1; m < 64; m <<= 1) fv += __shfl_xor(fv, m, 64);
        if (lane == 0) part[tt * 2 + wid] = fv;
    }
    __syncthreads();
    for (int tt = a; tt < 50; tt += 128)
        e[b * TT + t0 + tt] = part[tt * 2 + 0] + part[tt * 2 + 1];
}
__global__ __launch_bounds__(128) void k_energy(const float* pq, const float* PM, const float* cum,
                                                const float* weff, const void* att_v, float* e, const int* flag) {
    __shared__ float cumsh[80];
    __shared__ float part[50 * 2];
    if (*flag) energy_body<1>(pq, PM, cum, weff, att_v, e, cumsh, part);
    else       energy_body<0>(pq, PM, cum, weff, att_v, e, cumsh, part);
}

// ---------------- softmax + cum += align + ctx = align @ memory ------
__global__ __launch_bounds__(256) void k_softmax_ctx(const float* e, float* cum, const float* H1, float* ctx) {
    __shared__ float al[400];
    __shared__ float red[256];
    int b = blockIdx.x, tid = threadIdx.x;
    float m = -1e30f;
    for (int t = tid; t < TT; t += 256) { float v = e[b * TT + t]; al[t] = v; m = fmaxf(m, v); }
    red[tid] = m; __syncthreads();
    for (int st = 128; st > 0; st >>= 1) { if (tid < st) red[tid] = fmaxf(red[tid], red[tid + st]); __syncthreads(); }
    m = red[0]; __syncthreads();
    float s = 0.f;
    for (int t = tid; t < TT; t += 256) { float v = __expf(al[t] - m); al[t] = v; s += v; }
    red[tid] = s; __syncthreads();
    for (int st = 128; st > 0; st >>= 1) { if (tid < st) red[tid] += red[tid + st]; __syncthreads(); }
    float inv = 1.0f / red[0];
    __syncthreads();
    for (int t = tid; t < TT; t += 256) { float v = al[t] * inv; al[t] = v; cum[b * TT + t] += v; }
    __syncthreads();
    int d = tid;
    float acc0 = 0.f, acc1 = 0.f;
    for (int t = 0; t < TT; ++t) {
        float a_ = al[t];
        const float* row = H1 + ((size_t)t * BB + b) * EE;
        acc0 += a_ * row[d];
        acc1 += a_ * row[d + 256];
    }
    ctx[b * EE + d] = acc0; ctx[b * EE + d + 256] = acc1;
}

// ---------------- decoder LSTM cell: coalesced tiled GEMM over Wt2[k][u][g] -------
__global__ __launch_bounds__(512) void k_dec_lstm2(const float* PRE_t, const float* ctx, const float* hd_in,
                                                   const float* Wt2, const void* bbp,
                                                   float* hd_out, float* cd, const int* flag) {
    __shared__ float xs[896 * 9];
    int bt = blockIdx.x >> 4, ut = blockIdx.x & 15;
    int b0 = bt * 8, u0 = ut * 64;
    int tid = threadIdx.x;
    int u_l = tid & 63, bq = tid >> 6;
    int u = u0 + u_l, b = b0 + bq;
    int f32 = *flag;
    float ai, af, ag, ao;
    if (f32) {
        ai = ldf<1>(bbp, u);        af = ldf<1>(bbp, u + 1024);
        ag = ldf<1>(bbp, u + 2048); ao = ldf<1>(bbp, u + 3072);
    } else {
        ai = ldf<0>(bbp, u);        af = ldf<0>(bbp, u + 1024);
        ag = ldf<0>(bbp, u + 2048); ao = ldf<0>(bbp, u + 3072);
    }
    for (int ch = 0; ch < 2; ++ch) {
        __syncthreads();
        for (int idx = tid; idx < 896 * 8; idx += 512) {
            int b_l = idx / 896, kl = idx - b_l * 896;
            int k = ch * 896 + kl;
            int bb_ = b0 + b_l;
            float v;
            if (k < 256)      v = PRE_t[(size_t)bb_ * HH + k];
            else if (k < 768) v = ctx[(size_t)bb_ * EE + (k - 256)];
            else              v = hd_in[(size_t)bb_ * DD + (k - 768)];
            xs[kl * 9 + b_l] = v;
        }
        __syncthreads();
        const float4* wp = (const float4*)Wt2 + (size_t)(ch * 896) * 1024 + u;
        #pragma unroll 8
        for (int kl = 0; kl < 896; ++kl) {
            float4 w = wp[(size_t)kl * 1024];
            float x = xs[kl * 9 + bq];
            ai += w.x * x; af += w.y * x; ag += w.z * x; ao += w.w * x;
        }
    }
    float iv = sigm(ai), fv = sigm(af), gv = tanhf(ag), ov = sigm(ao);
    float c = cd[(size_t)b * DD + u];
    c = fv * c + iv * gv;
    cd[(size_t)b * DD + u] = c;
    hd_out[(size_t)b * DD + u] = ov * tanhf(c);
}

// ---------------- output projection + gate (coalesced via outWt[k][j]) -----------
template<int F32> __device__ __forceinline__
void dec_out_body(const float* hd, const float* ctx, const float* outWt, const void* outB,
                  void* dout, int t, float* xsh) {
    int b = blockIdx.x, tid = threadIdx.x;
    for (int idx = tid; idx < 1536; idx += 256)
        xsh[idx] = (idx < 1024) ? hd[(size_t)b * DD + idx] : ctx[(size_t)b * EE + (idx - 1024)];
    __syncthreads();
    if (tid < 240) {
        float a0 = 0, a1 = 0, a2 = 0, a3 = 0;
        for (int k = 0; k < 1536; k += 4) {
            a0 += outWt[(size_t)(k + 0) * 240 + tid] * xsh[k + 0];
            a1 += outWt[(size_t)(k + 1) * 240 + tid] * xsh[k + 1];
            a2 += outWt[(size_t)(k + 2) * 240 + tid] * xsh[k + 2];
            a3 += outWt[(size_t)(k + 3) * 240 + tid] * xsh[k + 3];
        }
        float acc = ldf<F32>(outB, tid) + ((a0 + a1) + (a2 + a3));
        int j = tid / 80, mm = tid - j * 80;
        int col = 3 * t + j;
        stf<F32>(dout, (size_t)b * 96000 + (size_t)mm * 1200 + col, acc);
        if (mm == 79) stf<F32>(dout, (size_t)24576000 + (size_t)b * 1200 + col, sigm(acc));
    }
}
__global__ __launch_bounds__(256) void k_dec_out2(const float* hd, const float* ctx, const float* outWt,
                                                  const void* outB, void* dout, int t, const int* flag) {
    __shared__ __align__(16) float xsh[1536];
    if (*flag) dec_out_body<1>(hd, ctx, outWt, outB, dout, t, xsh);
    else       dec_out_body<0>(hd, ctx, outWt, outB, dout, t, xsh);
}

// ---------------- postnet conv1 (80->512, k5 pad2) + bias; P1 bf16 -----
template<int F32> __device__ __forceinline__
void post1_body(const void* dout, const void* W, const void* bias, u16* P1, u16* msh) {
    int t0 = blockIdx.x * 64, o0 = blockIdx.y * 32, b = blockIdx.z;
    int tid = threadIdx.x;
    for (int idx = tid; idx < 80 * 68; idx += 256) {
        int i = idx / 68, rest = idx - i * 68;
        int t = t0 - 2 + rest;
        u16 v = 0;
        if (t >= 0 && t < T3) v = f2b(ldf<F32>(dout, (size_t)b * 96000 + (size_t)i * 1200 + t));
        msh[idx] = v;
    }
    __syncthreads();
    int ol = tid >> 3, tg = tid & 7;
    int o = o0 + ol, tl = tg * 8;
    float acc[8];
    float bv = ldf<F32>(bias, o);
    #pragma unroll
    for (int j = 0; j < 8; ++j) acc[j] = bv;
    size_t wrow = (size_t)o * 400;
    for (int i = 0; i < 80; ++i) {
        float xv[12];
        #pragma unroll
        for (int j = 0; j < 12; ++j) xv[j] = b2f(msh[i * 68 + tl + j]);
        #pragma unroll
        for (int k = 0; k < 5; ++k) {
            float w = ldf<F32>(W, wrow + i * 5 + k);
            #pragma unroll
            for (int j = 0; j < 8; ++j) acc[j] += w * xv[j + k];
        }
    }
    #pragma unroll
    for (int j = 0; j < 8; ++j) {
        int t = t0 + tl + j;
        if (t < T3) P1[((size_t)b * EE + o) * T3 + t] = f2b(acc[j]);
    }
}
__global__ __launch_bounds__(256) void k_post1(const void* dout, const void* W, const void* bias,
                                               u16* P1, const int* flag) {
    __shared__ u16 msh[80 * 68];
    if (*flag) post1_body<1>(dout, W, bias, P1, msh); else post1_body<0>(dout, W, bias, P1, msh);
}

// ---------------- postnet conv2 (512->80) over tanh(BN(P1)), + residual ----------
template<int F32> __device__ __forceinline__
void post2_body(const u16* P1, const float* mu, const float* rs, const void* g, const void* beta,
                const void* W2, const void* b2v, void* dout, float* tsh) {
    int t0 = blockIdx.x * 32, b = blockIdx.y;
    int tid = threadIdx.x;
    int tl = tid >> 3, mg = tid & 7;
    float acc[10];
    #pragma unroll
    for (int q = 0; q < 10; ++q) acc[q] = ldf<F32>(b2v, mg + 8 * q);
    for (int oc = 0; oc < 4; ++oc) {
        int o0 = oc * 128;
        __syncthreads();
        for (int idx = tid; idx < 128 * 36; idx += 256) {
            int i = idx / 36, rest = idx - i * 36;
            int t = t0 - 2 + rest;
            float v = 0.f;
            if (t >= 0 && t < T3) {
                int o = o0 + i;
                float raw = b2f(P1[((size_t)b * EE + o) * T3 + t]);
                v = tanhf((raw - mu[o]) * rs[o] * ldf<F32>(g, o) + ldf<F32>(beta, o));
            }
            tsh[i * 37 + rest] = v;
        }
        __syncthreads();
        for (int i = 0; i < 128; ++i) {
            float xv[5];
            #pragma unroll
            for (int k = 0; k < 5; ++k) xv[k] = tsh[i * 37 + tl + k];
            #pragma unroll
            for (int q = 0; q < 10; ++q) {
                int m = mg + 8 * q;
                size_t wp = ((size_t)m * 512 + o0 + i) * 5;
                acc[q] += ldf<F32>(W2, wp + 0) * xv[0];
                acc[q] += ldf<F32>(W2, wp + 1) * xv[1];
                acc[q] += ldf<F32>(W2, wp + 2) * xv[2];
                acc[q] += ldf<F32>(W2, wp + 3) * xv[3];
                acc[q] += ldf<F32>(W2, wp + 4) * xv[4];
            }
        }
    }
    int t = t0 + tl;
    if (t < T3) {
        #pragma unroll
        for (int q = 0; q < 10; ++q) {
            int m = mg + 8 * q;
            size_t idx = (size_t)b * 96000 + (size_t)m * 1200 + t;
            float res = ldf<F32>(dout, idx);
            stf<F32>(dout, (size_t)12288000 + idx, acc[q] + res);
        }
    }
}
__global__ __launch_bounds__(256) void k_post2(const u16* P1, const float* mu, const float* rs,
                                               const void* g, const void* beta, const void* W2,
                                               const void* b2v, void* dout, const int* flag) {
    __shared__ float tsh[128 * 37];
    if (*flag) post2_body<1>(P1, mu, rs, g, beta, W2, b2v, dout, tsh);
    else       post2_body<0>(P1, mu, rs, g, beta, W2, b2v, dout, tsh);
}

extern "C" void kernel_launch(void* const* d_in, const int* in_sizes, int n_in,
                              void* d_out, int out_size, void* d_ws, size_t ws_size,
                              hipStream_t stream) {
    const int*  text       = (const int*)d_in[0];
    const void* mels       = d_in[1];
    const void* emb        = d_in[2];
    const void* enc_conv_w = d_in[3];
    const void* enc_conv_b = d_in[4];
    const void* bn_g       = d_in[5];
    const void* bn_b       = d_in[6];
    const void* lstm_Wih   = d_in[7];
    const void* lstm_Whh   = d_in[8];
    const void* lstm_b     = d_in[9];
    const void* pre_W1     = d_in[10];
    const void* pre_b1     = d_in[11];
    const void* pre_W2     = d_in[12];
    const void* pre_b2     = d_in[13];
    const void* att_Wq     = d_in[14];
    const void* att_Wm     = d_in[15];
    const void* att_Wloc   = d_in[16];
    const void* att_v      = d_in[17];
    const void* dec_Wih    = d_in[18];
    const void* dec_Whh    = d_in[19];
    const void* dec_b      = d_in[20];
    const void* out_W      = d_in[21];
    const void* out_b      = d_in[22];
    const void* post_w1    = d_in[23];
    const void* post_b1    = d_in[24];
    const void* post_g     = d_in[25];
    const void* post_bta   = d_in[26];
    const void* post_w2    = d_in[27];
    const void* post_b2    = d_in[28];

    const size_t WS_NEED = 212049924;
    if (ws_size < WS_NEED) {
        fprintf(stderr, "kernel_launch: ws_size %zu < needed %zu\n", ws_size, WS_NEED);
        return;
    }
    // Encoder ping-pong: X(S0) -> Yf(S1) -> H0f(S0) -> Af(S1) -> Bf(S0) -> H1f(S1)
    // Encoder weights WtE (18.9MB) live in d_out scratch (outputs written later).
    // Decoder phase S0: PM 26.2M | Wt2 29.36M | outWt 1.47M | Wqt 0.52M | PRE_t 0.13M (all fp32)
    // Postnet: P1(u16 157.3M) at [0,157286400) — decoder-phase buffers dead by then.
    char* ws = (char*)d_ws;
    float* X    = (float*)(ws + 0);
    float* Yf   = (float*)(ws + 104857600);
    float* H0f  = (float*)(ws + 0);
    float* Af   = (float*)(ws + 104857600);
    float* Bf   = (float*)(ws + 0);
    float* H1f  = (float*)(ws + 104857600);
    float* PM    = (float*)(ws + 0);           // [0, 26214400)
    float* Wt2   = (float*)(ws + 26214400);    // [26214400, 55574528)
    float* outWt = (float*)(ws + 55574528);    // [55574528, 57049088)
    float* Wqt   = (float*)(ws + 57049088);    // [57049088, 57573376)
    float* PRE_t = (float*)(ws + 57573376);    // [57573376, 57704448)
    u16*   P1    = (u16*)(ws + 0);             // postnet
    float* WtE   = (float*)d_out;              // 18,874,368 B scratch during encoder
    char* SM = ws + 209715200;
    float* weff  = (float*)(SM + 0);
    float* encmu = (float*)(SM + 16384);
    float* encrs = (float*)(SM + 18432);
    float* pmu   = (float*)(SM + 20480);
    float* prs   = (float*)(SM + 22528);
    float* pq    = (float*)(SM + 24576);
    float* ebuf  = (float*)(SM + 90112);
    float* cum   = (float*)(SM + 294912);
    float* ctx   = (float*)(SM + 499712);
    float* hd0   = (float*)(SM + 761856);
    float* hd1   = (float*)(SM + 1286144);
    float* cd    = (float*)(SM + 1810432);
    int*   flag  = (int*)(SM + 2334720);

    k_detect<<<1, 256, 0, stream>>>(emb, flag);
    hipMemsetAsync(SM, 0, 2334720, stream);
    k_weff<<<1, 128, 0, stream>>>(att_Wloc, weff, flag);
    k_transEnc<<<dim3(6, 768), 256, 0, stream>>>(lstm_Wih, lstm_Whh, WtE, flag);

    // ---- encoder ----
    k_embed<<<dim3(512, 128), 256, 0, stream>>>(text, emb, X, flag);
    k_encconv<<<dim3(7, 16, 128), 256, 0, stream>>>(X, enc_conv_w, enc_conv_b, Yf, flag);
    k_bnstats<<<512, 256, 0, stream>>>(Yf, encmu, encrs, 400, 512, 128, 1);
    k_bnapply<<<dim3(7, 8, 128), 256, 0, stream>>>(Yf, encmu, encrs, bn_g, bn_b, H0f, flag);
    k_lstm2<<<128, 256, 0, stream>>>(H0f, Af, WtE, lstm_b, 0, flag);
    k_lstm2<<<128, 256, 0, stream>>>(Af, Bf, WtE, lstm_b, 1, flag);
    k_lstm2<<<128, 256, 0, stream>>>(Bf, H1f, WtE, lstm_b, 2, flag);

    // ---- decoder precompute (S0 free after layer-2 consumes Bf) ----
    k_transW<<<dim3(4, 1792), 256, 0, stream>>>(dec_Wih, dec_Whh, Wt2, flag);
    k_transOut<<<1536, 256, 0, stream>>>(out_W, outWt, flag);
    k_transWq<<<1024, 128, 0, stream>>>(att_Wq, Wqt, flag);
    k_pm<<<dim3(50, 128), 128, 0, stream>>>(H1f, att_Wm, PM, flag);

    // ---- decoder scan ----
    for (int t = 0; t < TT; ++t) {
        float* hin  = (t & 1) ? hd1 : hd0;
        float* hout = (t & 1) ? hd0 : hd1;
        k_prenet_step<<<128, 256, 0, stream>>>(mels, pre_W1, pre_b1, pre_W2, pre_b2, PRE_t, t, flag);
        k_pq2<<<128, 128, 0, stream>>>(hin, Wqt, pq);
        k_energy<<<dim3(8, 128), 128, 0, stream>>>(pq, PM, cum, weff, att_v, ebuf, flag);
        k_softmax_ctx<<<128, 256, 0, stream>>>(ebuf, cum, H1f, ctx);
        k_dec_lstm2<<<256, 512, 0, stream>>>(PRE_t, ctx, hin, Wt2, dec_b, hout, cd, flag);
        k_dec_out2<<<128, 256, 0, stream>>>(hout, ctx, outWt, out_b, d_out, t, flag);
    }

    // ---- postnet ----
    k_post1<<<dim3(19, 16, 128), 256, 0, stream>>>(d_out, post_w1, post_b1, P1, flag);
    k_bnstats<<<512, 256, 0, stream>>>(P1, pmu, prs, 1200, 512, 128, 0);
    k_post2<<<dim3(38, 128), 256, 0, stream>>>(P1, pmu, prs, post_g, post_bta, post_w2, post_b2, d_out, flag);
}